// Round 2
// baseline (4024.416 us; speedup 1.0000x reference)
//
#include <hip/hip_runtime.h>
#include <hip/hip_cooperative_groups.h>

typedef unsigned short u16;
typedef __bf16 bf16x8 __attribute__((ext_vector_type(8)));
typedef float f32x4 __attribute__((ext_vector_type(4)));

#define T_STEPS 64
#define BATCH 32
#define HDIM 1024
#define EDIM 512
#define VDIM 32000
#define GDIM 4096  // 4*H

// fp32 -> bf16 round-to-nearest-even (matches XLA convert)
__device__ __forceinline__ u16 f2b(float v) {
  unsigned x = __float_as_uint(v);
  return (u16)((x + 0x7fffu + ((x >> 16) & 1u)) >> 16);
}

// async global->LDS, 16B per lane; lds dest = wave-uniform base + lane*16
__device__ __forceinline__ void gload16(const void* g, void* l) {
  __builtin_amdgcn_global_load_lds(
      (const __attribute__((address_space(1))) void*)g,
      (__attribute__((address_space(3))) void*)l, 16, 0, 0);
}

__device__ __forceinline__ f32x4 mfma16(bf16x8 a, bf16x8 b, f32x4 c) {
  return __builtin_amdgcn_mfma_f32_16x16x32_bf16(a, b, c, 0, 0, 0);
}

// swizzled LDS fragment read: tile rows are 1024 bf16 (2048 B), XOR-swizzled
// byte ^= (row&7)<<4 to spread 16-lane row-column reads across all banks.
__device__ __forceinline__ bf16x8 lds_frag(const u16* base, int row, int k) {
  return *reinterpret_cast<const bf16x8*>(
      (const char*)base + row * 2048 + ((k * 2) ^ ((row & 7) << 4)));
}

// ---------------- prep kernels ----------------

__global__ __launch_bounds__(256) void gather_emb_k(
    const int* __restrict__ x, const float* __restrict__ emb,
    u16* __restrict__ A) {
  int bt = blockIdx.x;
  int tok = x[bt];
  const float* src = emb + (size_t)tok * EDIM;
  u16* dst = A + (size_t)bt * EDIM;
  for (int i = threadIdx.x; i < EDIM; i += 256) dst[i] = f2b(src[i]);
}

// in: fp32 [K][N] row-major  ->  out: bf16 [N][K] row-major
__global__ __launch_bounds__(256) void transpose_cvt_k(
    const float* __restrict__ in, u16* __restrict__ out, int K, int N) {
  __shared__ u16 tile[64][72];
  int n0 = blockIdx.x * 64, k0 = blockIdx.y * 64;
  int tid = threadIdx.x;
  int cr = tid >> 6;   // 0..3
  int cc = tid & 63;
#pragma unroll
  for (int rr = 0; rr < 16; ++rr) {
    int r = rr * 4 + cr;  // k index within tile
    tile[cc][r] = f2b(in[(size_t)(k0 + r) * N + n0 + cc]);
  }
  __syncthreads();
#pragma unroll
  for (int rr = 0; rr < 16; ++rr) {
    int r = rr * 4 + cr;  // n index within tile
    out[(size_t)(n0 + r) * K + k0 + cc] = tile[r][cc];
  }
}

// U transpose with gate-permuted output rows: out row pn = nb*16 + g*4 + j
// for input col n = g*1024 + nb*4 + j. Block nb's 16 z-cols become contiguous.
__global__ __launch_bounds__(256) void transpose_cvt_permU_k(
    const float* __restrict__ in, u16* __restrict__ out) {
  const int K = HDIM, N = GDIM;
  __shared__ u16 tile[64][72];
  int n0 = blockIdx.x * 64, k0 = blockIdx.y * 64;
  int tid = threadIdx.x;
  int cr = tid >> 6;
  int cc = tid & 63;
#pragma unroll
  for (int rr = 0; rr < 16; ++rr) {
    int r = rr * 4 + cr;
    tile[cc][r] = f2b(in[(size_t)(k0 + r) * N + n0 + cc]);
  }
  __syncthreads();
#pragma unroll
  for (int rr = 0; rr < 16; ++rr) {
    int r = rr * 4 + cr;
    int n = n0 + r;
    int g = n >> 10, c = n & 1023;
    int pn = ((c >> 2) << 4) + (g << 2) + (c & 3);
    out[(size_t)pn * K + k0 + cc] = tile[r][cc];
  }
}

// init h double-buffer slot 0 with bf16(state_h)
__global__ __launch_bounds__(256) void init_state_k(
    const float* __restrict__ h0, u16* __restrict__ hbuf) {
  int i = blockIdx.x * 256 + threadIdx.x;  // 32768 total
  hbuf[i] = f2b(h0[i]);
}

// ---------------- bf16 MFMA GEMM: C[M][N] = A[M][K] * BT[N][K]^T + bias ----
// 128x128 tile, BK=64, 256 threads (4 waves in 2x2 quadrants), m97 structure.
// Block remap: consecutive blocks sweep M (share one B panel; A L2-resident).

__global__ __launch_bounds__(256) void gemm_bf16_k(
    const u16* __restrict__ A,    // [M][K] bf16
    const u16* __restrict__ BT,   // [N][K] bf16 (B transposed)
    const float* __restrict__ bias,  // [N] or nullptr
    float* __restrict__ C,        // [M][N] fp32
    int M, int N, int K) {
  __shared__ u16 As[128 * 64];
  __shared__ u16 Bs[128 * 64];
  const int tid = threadIdx.x;
  const int w = tid >> 6, lane = tid & 63;
  const int lo16 = lane & 15, hi4 = lane >> 4;
  // M-major remap for B-panel L2 reuse
  const int nmb = gridDim.y;
  const int bid = blockIdx.y * gridDim.x + blockIdx.x;
  const int m0 = (bid % nmb) * 128, n0 = (bid / nmb) * 128;
  const int wr = w >> 1, wc = w & 1;  // 64x64 quadrant per wave
  f32x4 acc[4][4] = {};

  const int srow = lane >> 3;        // 0..7 (row within 8-row chunk)
  const int scol = (lane & 7) * 8;   // element col offset (8 bf16 = 16B)

  for (int k0 = 0; k0 < K; k0 += 64) {
    __syncthreads();  // protect LDS from previous iteration's readers
#pragma unroll
    for (int r = 0; r < 4; ++r) {
      int blkrow = (r * 4 + w) * 8 + srow;  // 0..127
      gload16(A + (size_t)(m0 + blkrow) * K + k0 + scol,
              As + (r * 4 + w) * 512);
      gload16(BT + (size_t)(n0 + blkrow) * K + k0 + scol,
              Bs + (r * 4 + w) * 512);
    }
    __syncthreads();  // drains vmcnt (compiler emits waitcnt before barrier)

    bf16x8 af[4][2], bfr[4][2];
#pragma unroll
    for (int mi = 0; mi < 4; ++mi)
#pragma unroll
      for (int kk = 0; kk < 2; ++kk)
        af[mi][kk] = *reinterpret_cast<const bf16x8*>(
            As + (wr * 64 + mi * 16 + lo16) * 64 + kk * 32 + hi4 * 8);
#pragma unroll
    for (int nj = 0; nj < 4; ++nj)
#pragma unroll
      for (int kk = 0; kk < 2; ++kk)
        bfr[nj][kk] = *reinterpret_cast<const bf16x8*>(
            Bs + (wc * 64 + nj * 16 + lo16) * 64 + kk * 32 + hi4 * 8);
#pragma unroll
    for (int mi = 0; mi < 4; ++mi)
#pragma unroll
      for (int nj = 0; nj < 4; ++nj)
#pragma unroll
        for (int kk = 0; kk < 2; ++kk)
          acc[mi][nj] = mfma16(af[mi][kk], bfr[nj][kk], acc[mi][nj]);
  }

  const int row0 = m0 + wr * 64, col0 = n0 + wc * 64;
#pragma unroll
  for (int mi = 0; mi < 4; ++mi) {
#pragma unroll
    for (int nj = 0; nj < 4; ++nj) {
      int col = col0 + nj * 16 + lo16;
      float bv = bias ? bias[col] : 0.f;
#pragma unroll
      for (int j = 0; j < 4; ++j) {
        int row = row0 + mi * 16 + hi4 * 4 + j;
        C[(size_t)row * N + col] = acc[mi][nj][j] + bv;
      }
    }
  }
}

// ---------------- persistent cooperative LSTM scan ----------------
// 256 blocks x 256 threads, one block per CU. Block nb owns h-cols
// [4nb, 4nb+4) x 4 gates = 16 z-cols; its U slice (16x1024 bf16, permuted
// rows of UT2) lives in LDS for all 64 steps. Per step: stage h (32x1024
// bf16) into LDS, 4 waves each MFMA a K=256 quarter, reduce z partials in
// LDS, gate math (c in registers), broadcast new h via double-buffered
// global + grid.sync().

__global__ __launch_bounds__(256) void lstm_seq_k(
    const float* __restrict__ xW,   // [2048][4096] (bias included)
    const u16* __restrict__ UT2,    // [4096 permuted][1024] bf16
    u16* __restrict__ hbuf,         // [2][32][1024] bf16 double buffer
    const float* __restrict__ c0,   // [32][1024] fp32 initial c
    u16* __restrict__ seq,          // [2048][1024] bf16 out (logits A)
    float* __restrict__ out_hc) {   // [2][32][1024] fp32 final h, c
  cooperative_groups::grid_group grid = cooperative_groups::this_grid();
  __shared__ u16 Hs[32 * 1024];     // 64 KB, swizzled rows
  __shared__ u16 Us[16 * 1024];     // 32 KB, swizzled rows
  __shared__ float Zs[4 * 32 * 17]; // padded z partials
  const int tid = threadIdx.x;
  const int w = tid >> 6, lane = tid & 63;
  const int lo16 = lane & 15, hi4 = lane >> 4;
  const int nb = blockIdx.x;

  // stage U slice once (pre-swizzled source -> linear LDS == swizzled tile)
#pragma unroll
  for (int p = 0; p < 8; ++p) {
    int o = p * 4096 + tid * 16;
    int row = o >> 11, cb = o & 2047;
    int sc = (cb ^ ((row & 7) << 4)) >> 1;
    gload16(UT2 + (size_t)(nb * 16 + row) * HDIM + sc,
            (char*)Us + p * 4096 + w * 1024);
  }

  const int b_g = tid >> 2, j_g = tid & 3;  // gate-math assignment
  const int col_g = nb * 4 + j_g;
  float creg = 0.f;
  if (tid < 128) creg = c0[b_g * HDIM + col_g];
  __syncthreads();  // Us ready

  for (int t = 0; t < T_STEPS; ++t) {
    const u16* hcur = hbuf + (size_t)(t & 1) * (BATCH * HDIM);
    u16* hnext = hbuf + (size_t)((t + 1) & 1) * (BATCH * HDIM);

    // issue xW reads early (consumed after z-reduce)
    float xw0 = 0.f, xw1 = 0.f, xw2 = 0.f, xw3 = 0.f;
    if (tid < 128) {
      const float* xrow = xW + (size_t)(b_g * T_STEPS + t) * GDIM + col_g;
      xw0 = xrow[0]; xw1 = xrow[1024]; xw2 = xrow[2048]; xw3 = xrow[3072];
    }

    // stage h tile (pre-swizzled source)
#pragma unroll
    for (int p = 0; p < 16; ++p) {
      int o = p * 4096 + tid * 16;
      int row = o >> 11, cb = o & 2047;
      int sc = (cb ^ ((row & 7) << 4)) >> 1;
      gload16(hcur + (size_t)row * HDIM + sc,
              (char*)Hs + p * 4096 + w * 1024);
    }
    __syncthreads();

    // wave w: K quarter [w*256, w*256+256)
    f32x4 acc0 = {}, acc1 = {};
#pragma unroll
    for (int kc = 0; kc < 8; ++kc) {
      int k = w * 256 + kc * 32 + hi4 * 8;
      bf16x8 bf = lds_frag(Us, lo16, k);
      acc0 = mfma16(lds_frag(Hs, lo16, k), bf, acc0);
      acc1 = mfma16(lds_frag(Hs, 16 + lo16, k), bf, acc1);
    }
    float* Zw = Zs + w * 544;
#pragma unroll
    for (int j = 0; j < 4; ++j) {
      Zw[(hi4 * 4 + j) * 17 + lo16] = acc0[j];
      Zw[(16 + hi4 * 4 + j) * 17 + lo16] = acc1[j];
    }
    __syncthreads();

    if (tid < 128) {
      float z[4] = {xw0, xw1, xw2, xw3};
#pragma unroll
      for (int g = 0; g < 4; ++g)
#pragma unroll
        for (int ww = 0; ww < 4; ++ww)
          z[g] += Zs[ww * 544 + b_g * 17 + g * 4 + j_g];
      float ig = 1.f / (1.f + __expf(-z[0]));
      float fg = 1.f / (1.f + __expf(-z[1]));
      float gg = tanhf(z[2]);
      float og = 1.f / (1.f + __expf(-z[3]));
      float cn = fg * creg + ig * gg;
      creg = cn;
      float hn = og * tanhf(cn);
      u16 hb = f2b(hn);
      __hip_atomic_store(&hnext[b_g * HDIM + col_g], hb, __ATOMIC_RELAXED,
                         __HIP_MEMORY_SCOPE_AGENT);
      seq[(size_t)(b_g * T_STEPS + t) * HDIM + col_g] = hb;
      if (t == T_STEPS - 1) {
        out_hc[b_g * HDIM + col_g] = hn;
        out_hc[BATCH * HDIM + b_g * HDIM + col_g] = cn;
      }
    }
    __threadfence();
    grid.sync();
  }
}

// ---------------- launcher ----------------

extern "C" void kernel_launch(void* const* d_in, const int* in_sizes, int n_in,
                              void* d_out, int out_size, void* d_ws,
                              size_t ws_size, hipStream_t stream) {
  const int* x = (const int*)d_in[0];
  const float* state_h = (const float*)d_in[1];
  const float* state_c = (const float*)d_in[2];
  const float* emb = (const float*)d_in[3];
  const float* W = (const float*)d_in[4];
  const float* U = (const float*)d_in[5];
  const float* bvec = (const float*)d_in[6];
  const float* dW = (const float*)d_in[7];
  const float* db = (const float*)d_in[8];
  float* out = (float*)d_out;
  char* ws = (char*)d_ws;

  size_t off = 0;
  auto alloc = [&](size_t bytes) {
    void* p = ws + off;
    off += (bytes + 255) & ~(size_t)255;
    return p;
  };
  u16* A_emb = (u16*)alloc(2048ull * EDIM * 2);      //  2.0 MB
  u16* WbT   = (u16*)alloc((size_t)GDIM * EDIM * 2); //  4.0 MB
  u16* UT2   = (u16*)alloc((size_t)GDIM * HDIM * 2); //  8.4 MB (permuted)
  u16* DbT   = (u16*)alloc((size_t)VDIM * HDIM * 2); // 65.5 MB
  float* xW  = (float*)alloc(2048ull * GDIM * 4);    // 33.6 MB
  u16* seq   = (u16*)alloc(2048ull * HDIM * 2);      //  4.2 MB
  u16* hbuf  = (u16*)alloc(2ull * BATCH * HDIM * 2); //  128 KB double buffer
  if (off > ws_size) return;  // ~117.8 MB needed

  gather_emb_k<<<2048, 256, 0, stream>>>(x, emb, A_emb);
  transpose_cvt_k<<<dim3(GDIM / 64, EDIM / 64), 256, 0, stream>>>(W, WbT, EDIM, GDIM);
  transpose_cvt_permU_k<<<dim3(GDIM / 64, HDIM / 64), 256, 0, stream>>>(U, UT2);
  transpose_cvt_k<<<dim3(VDIM / 64, HDIM / 64), 256, 0, stream>>>(dW, DbT, HDIM, VDIM);
  init_state_k<<<128, 256, 0, stream>>>(state_h, hbuf);

  // xW = emb @ W + b : [2048][4096]
  gemm_bf16_k<<<dim3(GDIM / 128, 2048 / 128), 256, 0, stream>>>(
      A_emb, WbT, bvec, xW, 2048, GDIM, EDIM);

  // persistent cooperative LSTM scan (all 64 timesteps)
  {
    const float* xW_p = xW;
    const u16* UT2_p = UT2;
    u16* hbuf_p = hbuf;
    const float* c0_p = state_c;
    u16* seq_p = seq;
    float* outhc_p = out + 65536000ull;
    void* args[] = {&xW_p, &UT2_p, &hbuf_p, &c0_p, &seq_p, &outhc_p};
    hipLaunchCooperativeKernel((const void*)lstm_seq_k, dim3(256), dim3(256),
                               args, 0, stream);
  }

  // logits = seq @ dense_W + dense_b : [2048][32000]
  gemm_bf16_k<<<dim3(VDIM / 128, 2048 / 128), 256, 0, stream>>>(
      seq, DbT, db, out, 2048, VDIM, HDIM);
}

// Round 3
// 736.900 us; speedup vs baseline: 5.4613x; 5.4613x over previous
//
#include <hip/hip_runtime.h>

typedef unsigned short u16;
typedef __bf16 bf16x8 __attribute__((ext_vector_type(8)));
typedef float f32x4 __attribute__((ext_vector_type(4)));

#define T_STEPS 64
#define BATCH 32
#define HDIM 1024
#define EDIM 512
#define VDIM 32000
#define GDIM 4096  // 4*H

// fp32 -> bf16 round-to-nearest-even (matches XLA convert)
__device__ __forceinline__ u16 f2b(float v) {
  unsigned x = __float_as_uint(v);
  return (u16)((x + 0x7fffu + ((x >> 16) & 1u)) >> 16);
}

// async global->LDS, 16B per lane; lds dest = wave-uniform base + lane*16
__device__ __forceinline__ void gload16(const void* g, void* l) {
  __builtin_amdgcn_global_load_lds(
      (const __attribute__((address_space(1))) void*)g,
      (__attribute__((address_space(3))) void*)l, 16, 0, 0);
}

__device__ __forceinline__ f32x4 mfma16(bf16x8 a, bf16x8 b, f32x4 c) {
  return __builtin_amdgcn_mfma_f32_16x16x32_bf16(a, b, c, 0, 0, 0);
}

// ---------------- prep kernels ----------------

__global__ __launch_bounds__(256) void gather_emb_k(
    const int* __restrict__ x, const float* __restrict__ emb,
    u16* __restrict__ A) {
  int bt = blockIdx.x;
  int tok = x[bt];
  const float* src = emb + (size_t)tok * EDIM;
  u16* dst = A + (size_t)bt * EDIM;
  for (int i = threadIdx.x; i < EDIM; i += 256) dst[i] = f2b(src[i]);
}

// in: fp32 [K][N] row-major  ->  out: bf16 [N][K] row-major
__global__ __launch_bounds__(256) void transpose_cvt_k(
    const float* __restrict__ in, u16* __restrict__ out, int K, int N) {
  __shared__ u16 tile[64][72];
  int n0 = blockIdx.x * 64, k0 = blockIdx.y * 64;
  int tid = threadIdx.x;
  int cr = tid >> 6;   // 0..3
  int cc = tid & 63;
#pragma unroll
  for (int rr = 0; rr < 16; ++rr) {
    int r = rr * 4 + cr;  // k index within tile
    tile[cc][r] = f2b(in[(size_t)(k0 + r) * N + n0 + cc]);
  }
  __syncthreads();
#pragma unroll
  for (int rr = 0; rr < 16; ++rr) {
    int r = rr * 4 + cr;  // n index within tile
    out[(size_t)(n0 + r) * K + k0 + cc] = tile[r][cc];
  }
}

// U transpose with gate-permuted output rows: out row pn = m*16 + g*4 + j
// for input col n = g*1024 + m*4 + j. A 16-row block of UT2 = 4 h-cols x 4
// gates -> one 16-col z-tile has all gates for 4 h-cols.
__global__ __launch_bounds__(256) void transpose_cvt_permU_k(
    const float* __restrict__ in, u16* __restrict__ out) {
  const int K = HDIM, N = GDIM;
  __shared__ u16 tile[64][72];
  int n0 = blockIdx.x * 64, k0 = blockIdx.y * 64;
  int tid = threadIdx.x;
  int cr = tid >> 6;
  int cc = tid & 63;
#pragma unroll
  for (int rr = 0; rr < 16; ++rr) {
    int r = rr * 4 + cr;
    tile[cc][r] = f2b(in[(size_t)(k0 + r) * N + n0 + cc]);
  }
  __syncthreads();
#pragma unroll
  for (int rr = 0; rr < 16; ++rr) {
    int r = rr * 4 + cr;
    int n = n0 + r;
    int g = n >> 10, c = n & 1023;
    int pn = ((c >> 2) << 4) + (g << 2) + (c & 3);
    out[(size_t)pn * K + k0 + cc] = tile[r][cc];
  }
}

// init h0 (bf16) and c (fp32 state in ws) — every call (ws not re-poisoned)
__global__ __launch_bounds__(256) void init_state_k(
    const float* __restrict__ h0, const float* __restrict__ c0,
    u16* __restrict__ h0b, float* __restrict__ c_ws) {
  int i = blockIdx.x * 256 + threadIdx.x;  // 32768 total
  h0b[i] = f2b(h0[i]);
  c_ws[i] = c0[i];
}

// ---------------- bf16 MFMA GEMM: C[M][N] = A[M][K] * BT[N][K]^T + bias ----
// 128x128 tile, BK=64, 256 threads (4 waves in 2x2 quadrants), m97 structure.
// Block remap: consecutive blocks sweep M (share one B panel; A L2-resident).

__global__ __launch_bounds__(256) void gemm_bf16_k(
    const u16* __restrict__ A,    // [M][K] bf16
    const u16* __restrict__ BT,   // [N][K] bf16 (B transposed)
    const float* __restrict__ bias,  // [N] or nullptr
    float* __restrict__ C,        // [M][N] fp32
    int M, int N, int K) {
  __shared__ u16 As[128 * 64];
  __shared__ u16 Bs[128 * 64];
  const int tid = threadIdx.x;
  const int w = tid >> 6, lane = tid & 63;
  const int lo16 = lane & 15, hi4 = lane >> 4;
  // M-major remap for B-panel L2 reuse
  const int nmb = gridDim.y;
  const int bid = blockIdx.y * gridDim.x + blockIdx.x;
  const int m0 = (bid % nmb) * 128, n0 = (bid / nmb) * 128;
  const int wr = w >> 1, wc = w & 1;  // 64x64 quadrant per wave
  f32x4 acc[4][4] = {};

  const int srow = lane >> 3;        // 0..7 (row within 8-row chunk)
  const int scol = (lane & 7) * 8;   // element col offset (8 bf16 = 16B)

  for (int k0 = 0; k0 < K; k0 += 64) {
    __syncthreads();  // protect LDS from previous iteration's readers
#pragma unroll
    for (int r = 0; r < 4; ++r) {
      int blkrow = (r * 4 + w) * 8 + srow;  // 0..127
      gload16(A + (size_t)(m0 + blkrow) * K + k0 + scol,
              As + (r * 4 + w) * 512);
      gload16(BT + (size_t)(n0 + blkrow) * K + k0 + scol,
              Bs + (r * 4 + w) * 512);
    }
    __syncthreads();  // drains vmcnt (compiler emits waitcnt before barrier)

    bf16x8 af[4][2], bfr[4][2];
#pragma unroll
    for (int mi = 0; mi < 4; ++mi)
#pragma unroll
      for (int kk = 0; kk < 2; ++kk)
        af[mi][kk] = *reinterpret_cast<const bf16x8*>(
            As + (wr * 64 + mi * 16 + lo16) * 64 + kk * 32 + hi4 * 8);
#pragma unroll
    for (int nj = 0; nj < 4; ++nj)
#pragma unroll
      for (int kk = 0; kk < 2; ++kk)
        bfr[nj][kk] = *reinterpret_cast<const bf16x8*>(
            Bs + (wc * 64 + nj * 16 + lo16) * 64 + kk * 32 + hi4 * 8);
#pragma unroll
    for (int mi = 0; mi < 4; ++mi)
#pragma unroll
      for (int nj = 0; nj < 4; ++nj)
#pragma unroll
        for (int kk = 0; kk < 2; ++kk)
          acc[mi][nj] = mfma16(af[mi][kk], bfr[nj][kk], acc[mi][nj]);
  }

  const int row0 = m0 + wr * 64, col0 = n0 + wc * 64;
#pragma unroll
  for (int mi = 0; mi < 4; ++mi) {
#pragma unroll
    for (int nj = 0; nj < 4; ++nj) {
      int col = col0 + nj * 16 + lo16;
      float bv = bias ? bias[col] : 0.f;
#pragma unroll
      for (int j = 0; j < 4; ++j) {
        int row = row0 + mi * 16 + hi4 * 4 + j;
        C[(size_t)row * N + col] = acc[mi][nj][j] + bv;
      }
    }
  }
}

// ---------------- slim LSTM step ----------------
// 512 blocks x 256 threads (2 blocks/CU). Block = one 16x16 output tile:
// batch-tile bt (16 rows) x z-tile zt (4 h-cols x 4 gates, permuted U rows).
// 4 waves split K=1024 into quarters; A (h) and B (U) fragments are loaded
// DIRECTLY from global (L2-hot; zero reuse within block -> LDS staging would
// only add barriers). One __syncthreads, 4-way z reduce in LDS, fused gates.
// seq doubles as the h history: step t reads rows (b*64+t-1), writes (b*64+t).

__global__ __launch_bounds__(256) void lstm_step2_k(
    const float* __restrict__ xW,    // [2048][4096] (bias included)
    const u16* __restrict__ h_src,   // bf16, row b at h_src + b*h_stride
    int h_stride,
    const u16* __restrict__ UT2,     // [4096 permuted][1024] bf16
    float* __restrict__ c_ws,        // [32][1024] fp32 state (in/out)
    u16* __restrict__ seq,           // [2048][1024] bf16
    float* __restrict__ out_hc,      // final h,c (fp32) or nullptr
    int t) {
  __shared__ float Zs[4][16][17];
  const int tid = threadIdx.x;
  const int w = tid >> 6, lane = tid & 63;
  const int lo16 = lane & 15, hi4 = lane >> 4;
  const int zt = blockIdx.x >> 1;   // 0..255
  const int bt = blockIdx.x & 1;    // 0..1

  const u16* arow = h_src + (size_t)(bt * 16 + lo16) * h_stride;
  const u16* brow = UT2 + (size_t)(zt * 16 + lo16) * HDIM;

  f32x4 acc = {};
#pragma unroll
  for (int kc = 0; kc < 8; ++kc) {
    int k = w * 256 + kc * 32 + hi4 * 8;
    bf16x8 a = *reinterpret_cast<const bf16x8*>(arow + k);
    bf16x8 b = *reinterpret_cast<const bf16x8*>(brow + k);
    acc = mfma16(a, b, acc);
  }
#pragma unroll
  for (int j = 0; j < 4; ++j) Zs[w][hi4 * 4 + j][lo16] = acc[j];
  __syncthreads();

  if (tid < 64) {
    int bb = tid >> 2, j = tid & 3;
    int b = bt * 16 + bb;
    int hcol = zt * 4 + j;
    float z[4];
#pragma unroll
    for (int g = 0; g < 4; ++g) {
      float s = xW[(size_t)(b * T_STEPS + t) * GDIM + g * HDIM + hcol];
#pragma unroll
      for (int ww = 0; ww < 4; ++ww) s += Zs[ww][bb][g * 4 + j];
      z[g] = s;
    }
    size_t cidx = (size_t)b * HDIM + hcol;
    float c_old = c_ws[cidx];
    float ig = 1.f / (1.f + __expf(-z[0]));
    float fg = 1.f / (1.f + __expf(-z[1]));
    float gg = tanhf(z[2]);
    float og = 1.f / (1.f + __expf(-z[3]));
    float cn = fg * c_old + ig * gg;
    float hn = og * tanhf(cn);
    c_ws[cidx] = cn;
    seq[(size_t)(b * T_STEPS + t) * HDIM + hcol] = f2b(hn);
    if (out_hc) {
      out_hc[cidx] = hn;
      out_hc[BATCH * HDIM + cidx] = cn;
    }
  }
}

// ---------------- launcher ----------------

extern "C" void kernel_launch(void* const* d_in, const int* in_sizes, int n_in,
                              void* d_out, int out_size, void* d_ws,
                              size_t ws_size, hipStream_t stream) {
  const int* x = (const int*)d_in[0];
  const float* state_h = (const float*)d_in[1];
  const float* state_c = (const float*)d_in[2];
  const float* emb = (const float*)d_in[3];
  const float* W = (const float*)d_in[4];
  const float* U = (const float*)d_in[5];
  const float* bvec = (const float*)d_in[6];
  const float* dW = (const float*)d_in[7];
  const float* db = (const float*)d_in[8];
  float* out = (float*)d_out;
  char* ws = (char*)d_ws;

  size_t off = 0;
  auto alloc = [&](size_t bytes) {
    void* p = ws + off;
    off += (bytes + 255) & ~(size_t)255;
    return p;
  };
  u16* A_emb = (u16*)alloc(2048ull * EDIM * 2);      //  2.0 MB
  u16* WbT   = (u16*)alloc((size_t)GDIM * EDIM * 2); //  4.0 MB
  u16* UT2   = (u16*)alloc((size_t)GDIM * HDIM * 2); //  8.4 MB (permuted)
  u16* DbT   = (u16*)alloc((size_t)VDIM * HDIM * 2); // 65.5 MB
  float* xW  = (float*)alloc(2048ull * GDIM * 4);    // 33.6 MB
  u16* seq   = (u16*)alloc(2048ull * HDIM * 2);      //  4.2 MB
  u16* h0b   = (u16*)alloc((size_t)BATCH * HDIM * 2);
  float* c_ws = (float*)alloc((size_t)BATCH * HDIM * 4);
  if (off > ws_size) return;  // ~117.8 MB needed

  gather_emb_k<<<2048, 256, 0, stream>>>(x, emb, A_emb);
  transpose_cvt_k<<<dim3(GDIM / 64, EDIM / 64), 256, 0, stream>>>(W, WbT, EDIM, GDIM);
  transpose_cvt_permU_k<<<dim3(GDIM / 64, HDIM / 64), 256, 0, stream>>>(U, UT2);
  transpose_cvt_k<<<dim3(VDIM / 64, HDIM / 64), 256, 0, stream>>>(dW, DbT, HDIM, VDIM);
  init_state_k<<<128, 256, 0, stream>>>(state_h, state_c, h0b, c_ws);

  // xW = emb @ W + b : [2048][4096]
  gemm_bf16_k<<<dim3(GDIM / 128, 2048 / 128), 256, 0, stream>>>(
      A_emb, WbT, bvec, xW, 2048, GDIM, EDIM);

  // LSTM scan: 64 slim step kernels; seq is the h history
  for (int t = 0; t < T_STEPS; ++t) {
    const u16* h_src = (t == 0) ? h0b : (seq + (size_t)(t - 1) * HDIM);
    int h_stride = (t == 0) ? HDIM : T_STEPS * HDIM;
    float* outhc = (t == T_STEPS - 1) ? (out + 65536000ull) : nullptr;
    lstm_step2_k<<<512, 256, 0, stream>>>(xW, h_src, h_stride, UT2, c_ws, seq,
                                          outhc, t);
  }

  // logits = seq @ dense_W + dense_b : [2048][32000]
  gemm_bf16_k<<<dim3(VDIM / 128, 2048 / 128), 256, 0, stream>>>(
      seq, DbT, db, out, 2048, VDIM, HDIM);
}

// Round 5
// 647.119 us; speedup vs baseline: 6.2190x; 1.1387x over previous
//
#include <hip/hip_runtime.h>

typedef unsigned short u16;
typedef __bf16 bf16x8 __attribute__((ext_vector_type(8)));
typedef float f32x4 __attribute__((ext_vector_type(4)));
typedef u16 u16x8 __attribute__((ext_vector_type(8)));

#define T_STEPS 64
#define BATCH 32
#define HDIM 1024
#define EDIM 512
#define VDIM 32000
#define GDIM 4096  // 4*H

// fp32 -> bf16 round-to-nearest-even (matches XLA convert)
__device__ __forceinline__ u16 f2b(float v) {
  unsigned x = __float_as_uint(v);
  return (u16)((x + 0x7fffu + ((x >> 16) & 1u)) >> 16);
}

// async global->LDS, 16B per lane; lds dest = wave-uniform base + lane*16
__device__ __forceinline__ void gload16(const void* g, void* l) {
  __builtin_amdgcn_global_load_lds(
      (const __attribute__((address_space(1))) void*)g,
      (__attribute__((address_space(3))) void*)l, 16, 0, 0);
}

__device__ __forceinline__ f32x4 mfma16(bf16x8 a, bf16x8 b, f32x4 c) {
  return __builtin_amdgcn_mfma_f32_16x16x32_bf16(a, b, c, 0, 0, 0);
}

// ---------------- prep kernels ----------------

__global__ __launch_bounds__(256) void gather_emb_k(
    const int* __restrict__ x, const float* __restrict__ emb,
    u16* __restrict__ A) {
  int bt = blockIdx.x;
  int tok = x[bt];
  const float* src = emb + (size_t)tok * EDIM;
  u16* dst = A + (size_t)bt * EDIM;
  for (int i = threadIdx.x; i < EDIM; i += 256) dst[i] = f2b(src[i]);
}

// in: fp32 [K][N] row-major  ->  out: bf16 [N][K] row-major (16B stores)
__global__ __launch_bounds__(256) void transpose_cvt_k(
    const float* __restrict__ in, u16* __restrict__ out, int K, int N) {
  __shared__ u16 tile[64][80];  // row stride 160 B -> 16B-aligned rows
  int n0 = blockIdx.x * 64, k0 = blockIdx.y * 64;
  int tid = threadIdx.x;
  int cr = tid >> 6;   // 0..3
  int cc = tid & 63;
#pragma unroll
  for (int rr = 0; rr < 16; ++rr) {
    int r = rr * 4 + cr;  // k index within tile
    tile[cc][r] = f2b(in[(size_t)(k0 + r) * N + n0 + cc]);
  }
  __syncthreads();
  int wr2 = tid >> 3, c8 = (tid & 7) * 8;
#pragma unroll
  for (int rr = 0; rr < 2; ++rr) {
    int r = rr * 32 + wr2;  // n index within tile
    *reinterpret_cast<u16x8*>(&out[(size_t)(n0 + r) * K + k0 + c8]) =
        *reinterpret_cast<const u16x8*>(&tile[r][c8]);
  }
}

// U transpose with gate-permuted output rows: out row pn = m*16 + g*4 + j
// for input col n = g*1024 + m*4 + j.
__global__ __launch_bounds__(256) void transpose_cvt_permU_k(
    const float* __restrict__ in, u16* __restrict__ out) {
  const int K = HDIM, N = GDIM;
  __shared__ u16 tile[64][80];
  int n0 = blockIdx.x * 64, k0 = blockIdx.y * 64;
  int tid = threadIdx.x;
  int cr = tid >> 6;
  int cc = tid & 63;
#pragma unroll
  for (int rr = 0; rr < 16; ++rr) {
    int r = rr * 4 + cr;
    tile[cc][r] = f2b(in[(size_t)(k0 + r) * N + n0 + cc]);
  }
  __syncthreads();
  int wr2 = tid >> 3, c8 = (tid & 7) * 8;
#pragma unroll
  for (int rr = 0; rr < 2; ++rr) {
    int r = rr * 32 + wr2;
    int n = n0 + r;
    int g = n >> 10, c = n & 1023;
    int pn = ((c >> 2) << 4) + (g << 2) + (c & 3);
    *reinterpret_cast<u16x8*>(&out[(size_t)pn * K + k0 + c8]) =
        *reinterpret_cast<const u16x8*>(&tile[r][c8]);
  }
}

// init h0 (bf16) and c (fp32 state in ws) — every call (ws not re-poisoned)
__global__ __launch_bounds__(256) void init_state_k(
    const float* __restrict__ h0, const float* __restrict__ c0,
    u16* __restrict__ h0b, float* __restrict__ c_ws) {
  int i = blockIdx.x * 256 + threadIdx.x;  // 32768 total
  h0b[i] = f2b(h0[i]);
  c_ws[i] = c0[i];
}

// ---------------- m97-style 128x128 GEMM (used for xW only) ----------------

__global__ __launch_bounds__(256) void gemm_bf16_k(
    const u16* __restrict__ A, const u16* __restrict__ BT,
    const float* __restrict__ bias, float* __restrict__ C,
    int M, int N, int K) {
  __shared__ u16 As[128 * 64];
  __shared__ u16 Bs[128 * 64];
  const int tid = threadIdx.x;
  const int w = tid >> 6, lane = tid & 63;
  const int lo16 = lane & 15, hi4 = lane >> 4;
  const int nmb = gridDim.y;
  const int bid = blockIdx.y * gridDim.x + blockIdx.x;
  const int m0 = (bid % nmb) * 128, n0 = (bid / nmb) * 128;
  const int wr = w >> 1, wc = w & 1;
  f32x4 acc[4][4] = {};

  const int srow = lane >> 3;
  const int scol = (lane & 7) * 8;

  for (int k0 = 0; k0 < K; k0 += 64) {
    __syncthreads();
#pragma unroll
    for (int r = 0; r < 4; ++r) {
      int blkrow = (r * 4 + w) * 8 + srow;
      gload16(A + (size_t)(m0 + blkrow) * K + k0 + scol,
              As + (r * 4 + w) * 512);
      gload16(BT + (size_t)(n0 + blkrow) * K + k0 + scol,
              Bs + (r * 4 + w) * 512);
    }
    __syncthreads();

    bf16x8 af[4][2], bfr[4][2];
#pragma unroll
    for (int mi = 0; mi < 4; ++mi)
#pragma unroll
      for (int kk = 0; kk < 2; ++kk)
        af[mi][kk] = *reinterpret_cast<const bf16x8*>(
            As + (wr * 64 + mi * 16 + lo16) * 64 + kk * 32 + hi4 * 8);
#pragma unroll
    for (int nj = 0; nj < 4; ++nj)
#pragma unroll
      for (int kk = 0; kk < 2; ++kk)
        bfr[nj][kk] = *reinterpret_cast<const bf16x8*>(
            Bs + (wc * 64 + nj * 16 + lo16) * 64 + kk * 32 + hi4 * 8);
#pragma unroll
    for (int mi = 0; mi < 4; ++mi)
#pragma unroll
      for (int nj = 0; nj < 4; ++nj)
#pragma unroll
        for (int kk = 0; kk < 2; ++kk)
          acc[mi][nj] = mfma16(af[mi][kk], bfr[nj][kk], acc[mi][nj]);
  }

  const int row0 = m0 + wr * 64, col0 = n0 + wc * 64;
#pragma unroll
  for (int mi = 0; mi < 4; ++mi) {
#pragma unroll
    for (int nj = 0; nj < 4; ++nj) {
      int col = col0 + nj * 16 + lo16;
      float bv = bias ? bias[col] : 0.f;
#pragma unroll
      for (int j = 0; j < 4; ++j) {
        int row = row0 + mi * 16 + hi4 * 4 + j;
        C[(size_t)row * N + col] = acc[mi][nj][j] + bv;
      }
    }
  }
}

// ---------------- 256x256 8-phase GEMM (T1+T2+T3+T4+T5) ----------------
// 512 threads = 8 waves (2M x 4N). BK=64, 2 K-tiles per iteration, 8 phases.
// FIXED BUFFER ROLES (round-4 bug): even K-tiles ALWAYS in buf0, odd in
// buf1 — the schedule stages kt(2it+2) back into buf0 and kt(2it+3) into
// buf1, so the buffers never swap. Ledger (per wave outstanding): start 4,
// +2/phase to 12, VMW4 at phases 4/8 -> 4. Every region drains >=1 phase
// before first read; every stage issues >=1 phase after last reader's
// lgkmcnt(0)+barrier. Last iter k2/k3 clamp re-stages kt15 (regions with no
// remaining readers) keeping the ledger uniform.

#define STG_A(dst, h, kb)                                              \
  do {                                                                 \
    gload16(Abytes + offA[h][0] + (kb), (dst) + (h) * 16384 + w * 1024); \
    gload16(Abytes + offA[h][1] + (kb),                                \
            (dst) + (h) * 16384 + 8192 + w * 1024);                    \
  } while (0)
#define STG_B(dst, h, kb)                                              \
  do {                                                                 \
    gload16(Bbytes + offB[h][0] + (kb),                                \
            (dst) + 32768 + (h) * 16384 + w * 1024);                   \
    gload16(Bbytes + offB[h][1] + (kb),                                \
            (dst) + 32768 + (h) * 16384 + 8192 + w * 1024);            \
  } while (0)
#define VMW4 asm volatile("s_waitcnt vmcnt(4)" ::: "memory")

#define PHASE(cur, mih, njh, STG, WAIT)                                   \
  do {                                                                    \
    bf16x8 af[4][2], bfr[2][2];                                           \
    _Pragma("unroll") for (int u = 0; u < 4; ++u) {                       \
      af[u][0] = *reinterpret_cast<const bf16x8*>((cur) +                 \
                                                  aoff[(mih)*4 + u][0]);  \
      af[u][1] = *reinterpret_cast<const bf16x8*>((cur) +                 \
                                                  aoff[(mih)*4 + u][1]);  \
    }                                                                     \
    _Pragma("unroll") for (int v = 0; v < 2; ++v) {                       \
      bfr[v][0] = *reinterpret_cast<const bf16x8*>((cur) +                \
                                                   boff[(njh)*2 + v][0]); \
      bfr[v][1] = *reinterpret_cast<const bf16x8*>((cur) +                \
                                                   boff[(njh)*2 + v][1]); \
    }                                                                     \
    STG;                                                                  \
    __builtin_amdgcn_s_barrier();                                         \
    asm volatile("s_waitcnt lgkmcnt(0)" ::: "memory");                    \
    __builtin_amdgcn_s_setprio(1);                                        \
    _Pragma("unroll") for (int u = 0; u < 4; ++u)                         \
        _Pragma("unroll") for (int v = 0; v < 2; ++v) {                   \
      acc[(mih)*4 + u][(njh)*2 + v] =                                     \
          mfma16(af[u][0], bfr[v][0], acc[(mih)*4 + u][(njh)*2 + v]);     \
      acc[(mih)*4 + u][(njh)*2 + v] =                                     \
          mfma16(af[u][1], bfr[v][1], acc[(mih)*4 + u][(njh)*2 + v]);     \
    }                                                                     \
    __builtin_amdgcn_s_setprio(0);                                        \
    WAIT;                                                                 \
    __builtin_amdgcn_s_barrier();                                         \
  } while (0)

__global__ __launch_bounds__(512, 2) void gemm256_k(
    const u16* __restrict__ A,    // [M][K] bf16
    const u16* __restrict__ BT,   // [N][K] bf16
    const float* __restrict__ bias,
    float* __restrict__ C,        // [M][N] fp32
    int M, int N, int K) {
  __shared__ __attribute__((aligned(1024))) char smem[131072];
  const int tid = threadIdx.x;
  const int w = tid >> 6, lane = tid & 63;
  const int lo16 = lane & 15, hi4 = lane >> 4;
  const int wr = w >> 2, wc = w & 3;

  // XCD-bijective swizzle (gridDim.x % 8 == 0) + M-major panel mapping
  const int cpx = gridDim.x >> 3;
  const int bid = blockIdx.x;
  const int swz = (bid & 7) * cpx + (bid >> 3);
  const int nmb = M >> 8;
  const int m0 = (swz % nmb) << 8, n0 = (swz / nmb) << 8;

  const char* Abytes = (const char*)A;
  const char* Bbytes = (const char*)BT;
  const int K2 = K * 2;

  // per-thread stage source offsets (inverse st_16x32 swizzle decode)
  int offA[2][2], offB[2][2];
#pragma unroll
  for (int h = 0; h < 2; ++h)
#pragma unroll
    for (int i = 0; i < 2; ++i) {
      int o = h * 16384 + (i * 512 + tid) * 16;
      int s = o >> 10, q = o & 1023;
      int qp = q ^ (((q >> 9) & 1) << 5);
      int row = ((s >> 1) << 4) + (qp >> 6);
      int colb = ((s & 1) << 6) + (qp & 63);
      offA[h][i] = (m0 + row) * K2 + colb;
      offB[h][i] = (n0 + row) * K2 + colb;
    }

  // per-thread fragment LDS byte offsets (swizzled read addresses)
  int aoff[8][2], boff[4][2];
#pragma unroll
  for (int mi = 0; mi < 8; ++mi)
#pragma unroll
    for (int kk = 0; kk < 2; ++kk) {
      int r = (mi >> 2) * 128 + wr * 64 + (mi & 3) * 16 + lo16;
      int q = (r & 15) * 64 + hi4 * 16;
      int qs = q ^ (((q >> 9) & 1) << 5);
      aoff[mi][kk] = (((r >> 4) << 1) + kk) * 1024 + qs;
    }
#pragma unroll
  for (int nj = 0; nj < 4; ++nj)
#pragma unroll
    for (int kk = 0; kk < 2; ++kk) {
      int r = (nj >> 1) * 128 + wc * 32 + (nj & 1) * 16 + lo16;
      int q = (r & 15) * 64 + hi4 * 16;
      int qs = q ^ (((q >> 9) & 1) << 5);
      boff[nj][kk] = 32768 + (((r >> 4) << 1) + kk) * 1024 + qs;
    }

  f32x4 acc[8][4] = {};
  char* const bd = smem;           // even K-tiles (kt 2it) — never swaps
  char* const bo = smem + 65536;   // odd K-tiles (kt 2it+1)

  // prologue: kt0 complete in bd + kt1 halves A0,B0 in bo; drain kt0
  STG_A(bd, 0, 0);
  STG_B(bd, 0, 0);
  STG_A(bd, 1, 0);
  STG_B(bd, 1, 0);
  STG_A(bo, 0, 128);
  STG_B(bo, 0, 128);
  VMW4;
  __builtin_amdgcn_s_barrier();

  const int NITER = K >> 7;  // two BK=64 tiles per iteration (K % 128 == 0)
  for (int it = 0; it < NITER; ++it) {
    const int k1 = (it * 128 + 64) * 2;
    const int k2 = min(it * 128 + 128, K - 64) * 2;
    const int k3 = min(it * 128 + 192, K - 64) * 2;
    PHASE(bd, 0, 0, STG_A(bo, 1, k1), ((void)0));
    PHASE(bd, 0, 1, STG_B(bo, 1, k1), ((void)0));
    PHASE(bd, 1, 0, STG_A(bd, 0, k2), ((void)0));
    PHASE(bd, 1, 1, STG_B(bd, 0, k2), VMW4);
    PHASE(bo, 0, 0, STG_A(bd, 1, k2), ((void)0));
    PHASE(bo, 0, 1, STG_B(bd, 1, k2), ((void)0));
    PHASE(bo, 1, 0, STG_A(bo, 0, k3), ((void)0));
    PHASE(bo, 1, 1, STG_B(bo, 0, k3), VMW4);
  }

#pragma unroll
  for (int mi = 0; mi < 8; ++mi) {
    int row = m0 + (mi >> 2) * 128 + wr * 64 + (mi & 3) * 16 + hi4 * 4;
#pragma unroll
    for (int nj = 0; nj < 4; ++nj) {
      int col = n0 + (nj >> 1) * 128 + wc * 32 + (nj & 1) * 16 + lo16;
      float bv = bias ? bias[col] : 0.f;
#pragma unroll
      for (int j = 0; j < 4; ++j)
        C[(size_t)(row + j) * N + col] = acc[mi][nj][j] + bv;
    }
  }
}

// ---------------- slim LSTM step ----------------
// 512 blocks x 256 threads. Block = 16x16 output tile; 4 waves split K=1024;
// operands direct from global (L2-hot). xW loads hoisted above the K-loop so
// their HBM/L3 latency hides under the MFMA work.

__global__ __launch_bounds__(256) void lstm_step2_k(
    const float* __restrict__ xW,    // [2048][4096] (bias included)
    const u16* __restrict__ h_src,   // bf16, row b at h_src + b*h_stride
    int h_stride,
    const u16* __restrict__ UT2,     // [4096 permuted][1024] bf16
    float* __restrict__ c_ws,        // [32][1024] fp32 state (in/out)
    u16* __restrict__ seq,           // [2048][1024] bf16
    float* __restrict__ out_hc,      // final h,c (fp32) or nullptr
    int t) {
  __shared__ float Zs[4][16][17];
  const int tid = threadIdx.x;
  const int w = tid >> 6, lane = tid & 63;
  const int lo16 = lane & 15, hi4 = lane >> 4;
  const int zt = blockIdx.x >> 1;   // 0..255
  const int bt = blockIdx.x & 1;    // 0..1

  // hoisted xW prefetch (consumed after the z-reduce barrier)
  const int bb = tid >> 2, jg = tid & 3;
  float xw0 = 0.f, xw1 = 0.f, xw2 = 0.f, xw3 = 0.f;
  if (tid < 64) {
    const float* xrow =
        xW + (size_t)((bt * 16 + bb) * T_STEPS + t) * GDIM + zt * 4 + jg;
    xw0 = xrow[0];
    xw1 = xrow[1024];
    xw2 = xrow[2048];
    xw3 = xrow[3072];
  }

  const u16* arow = h_src + (size_t)(bt * 16 + lo16) * h_stride;
  const u16* brow = UT2 + (size_t)(zt * 16 + lo16) * HDIM;

  f32x4 acc = {};
#pragma unroll
  for (int kc = 0; kc < 8; ++kc) {
    int k = w * 256 + kc * 32 + hi4 * 8;
    bf16x8 a = *reinterpret_cast<const bf16x8*>(arow + k);
    bf16x8 b = *reinterpret_cast<const bf16x8*>(brow + k);
    acc = mfma16(a, b, acc);
  }
#pragma unroll
  for (int j = 0; j < 4; ++j) Zs[w][hi4 * 4 + j][lo16] = acc[j];
  __syncthreads();

  if (tid < 64) {
    int b = bt * 16 + bb;
    int hcol = zt * 4 + jg;
    float z[4] = {xw0, xw1, xw2, xw3};
#pragma unroll
    for (int g = 0; g < 4; ++g)
#pragma unroll
      for (int ww = 0; ww < 4; ++ww) z[g] += Zs[ww][bb][g * 4 + jg];
    size_t cidx = (size_t)b * HDIM + hcol;
    float c_old = c_ws[cidx];
    float ig = 1.f / (1.f + __expf(-z[0]));
    float fg = 1.f / (1.f + __expf(-z[1]));
    float gg = tanhf(z[2]);
    float og = 1.f / (1.f + __expf(-z[3]));
    float cn = fg * c_old + ig * gg;
    float hn = og * tanhf(cn);
    c_ws[cidx] = cn;
    seq[(size_t)(b * T_STEPS + t) * HDIM + hcol] = f2b(hn);
    if (out_hc) {
      out_hc[cidx] = hn;
      out_hc[BATCH * HDIM + cidx] = cn;
    }
  }
}

// ---------------- launcher ----------------

extern "C" void kernel_launch(void* const* d_in, const int* in_sizes, int n_in,
                              void* d_out, int out_size, void* d_ws,
                              size_t ws_size, hipStream_t stream) {
  const int* x = (const int*)d_in[0];
  const float* state_h = (const float*)d_in[1];
  const float* state_c = (const float*)d_in[2];
  const float* emb = (const float*)d_in[3];
  const float* W = (const float*)d_in[4];
  const float* U = (const float*)d_in[5];
  const float* bvec = (const float*)d_in[6];
  const float* dW = (const float*)d_in[7];
  const float* db = (const float*)d_in[8];
  float* out = (float*)d_out;
  char* ws = (char*)d_ws;

  size_t off = 0;
  auto alloc = [&](size_t bytes) {
    void* p = ws + off;
    off += (bytes + 255) & ~(size_t)255;
    return p;
  };
  u16* A_emb = (u16*)alloc(2048ull * EDIM * 2);      //  2.0 MB
  u16* WbT   = (u16*)alloc((size_t)GDIM * EDIM * 2); //  4.0 MB
  u16* UT2   = (u16*)alloc((size_t)GDIM * HDIM * 2); //  8.4 MB (permuted)
  u16* DbT   = (u16*)alloc((size_t)VDIM * HDIM * 2); // 65.5 MB
  float* xW  = (float*)alloc(2048ull * GDIM * 4);    // 33.6 MB
  u16* seq   = (u16*)alloc(2048ull * HDIM * 2);      //  4.2 MB
  u16* h0b   = (u16*)alloc((size_t)BATCH * HDIM * 2);
  float* c_ws = (float*)alloc((size_t)BATCH * HDIM * 4);
  if (off > ws_size) return;  // ~117.8 MB needed

  gather_emb_k<<<2048, 256, 0, stream>>>(x, emb, A_emb);
  transpose_cvt_k<<<dim3(GDIM / 64, EDIM / 64), 256, 0, stream>>>(W, WbT, EDIM, GDIM);
  transpose_cvt_permU_k<<<dim3(GDIM / 64, HDIM / 64), 256, 0, stream>>>(U, UT2);
  transpose_cvt_k<<<dim3(VDIM / 64, HDIM / 64), 256, 0, stream>>>(dW, DbT, HDIM, VDIM);
  init_state_k<<<128, 256, 0, stream>>>(state_h, state_c, h0b, c_ws);

  // xW = emb @ W + b : [2048][4096]
  gemm_bf16_k<<<dim3(GDIM / 128, 2048 / 128), 256, 0, stream>>>(
      A_emb, WbT, bvec, xW, 2048, GDIM, EDIM);

  // LSTM scan: 64 slim step kernels; seq is the h history
  for (int t = 0; t < T_STEPS; ++t) {
    const u16* h_src = (t == 0) ? h0b : (seq + (size_t)(t - 1) * HDIM);
    int h_stride = (t == 0) ? HDIM : T_STEPS * HDIM;
    float* outhc = (t == T_STEPS - 1) ? (out + 65536000ull) : nullptr;
    lstm_step2_k<<<512, 256, 0, stream>>>(xW, h_src, h_stride, UT2, c_ws, seq,
                                          outhc, t);
  }

  // logits = seq @ dense_W + dense_b : [2048][32000], 8x125=1000 blocks
  gemm256_k<<<dim3((2048 / 256) * (VDIM / 256)), 512, 0, stream>>>(
      seq, DbT, db, out, 2048, VDIM, HDIM);
}